// Round 4
// baseline (347.326 us; speedup 1.0000x reference)
//
#include <hip/hip_runtime.h>
#include <stdint.h>

#define N_NODES 100000
#define N_EDGES 1600000
#define NFEAT 256
#define NHID 64
#define N_ELEMS (N_NODES * NHID)   // 6,400,000

// R11: row-buckets of 128 rows; per-bucket LDS counting sort.
#define BSHIFT 7
#define NBUCK 782                  // ceil(100000/128)
#define CHUNK 4096                 // edges per bhist/bucket block
#define NBBLK ((N_EDGES + CHUNK - 1) / CHUNK)   // 391
#define CAP 2560                   // stage capacity; mean 2048, sigma ~45 -> +11s

// R13: gather metadata moved to LDS (lgkmcnt) so support gathers (vmcnt)
// pipeline across node boundaries. Block = 52 contiguous nodes, 4 waves x 13.
#define NPB 52                     // nodes per block
#define GBLK ((N_NODES + NPB - 1) / NPB)        // 1924
#define ECAP 1536                  // LDS edge records; mean 832, sigma 29 -> +24s

// Config (validated R6/R7): inputs f32, output f32, dropout = JAX partitionable
// threefry (key=(0,42), counter (0,i), bits = o0^o1).
//
// R12 post-mortem: per-node rec load + readlane forced s_waitcnt vmcnt(0)
//   (in-order counter) -> drained the previous node's gathers every node.
//   87 -> only 79us. R13 stages metadata in LDS: ds_read_b64 uniform-address
//   broadcast is on lgkmcnt, so the vmcnt gather queue never drains; no
//   readlanes at all (metadata used as wave-uniform vector operands).
//
// ws layout:
//   sums[128] f32 | hb[1024] i32 | scaleshift[128] f32 | bbase[1024] i32
//   | bcur[1024] i32 | rowptr[100004] i32 | wt[16384] ushort
//   | agg[6.4M] f32 | sorted[1.6M] int2
// support[6.4M] bf16 staged in d_out (dead before apply overwrites).
// bucketed[1.6M] int2 aliases agg (dead until gather writes agg).

typedef __attribute__((ext_vector_type(8))) short bf16x8;
typedef __attribute__((ext_vector_type(4))) float f32x4;

__device__ __forceinline__ unsigned short f2bf(float f) {
    uint32_t u = __float_as_uint(f);
    u += 0x7FFFu + ((u >> 16) & 1u);   // RNE
    return (unsigned short)(u >> 16);
}
__device__ __forceinline__ float bf2f(unsigned short u) {
    return __uint_as_float(((uint32_t)u) << 16);
}

// ---------------------------------------------------------------------------
// W^T prep: wt[n][k] = bf16(W[k][n])
// ---------------------------------------------------------------------------
__global__ __launch_bounds__(256) void wtprep_kernel(const float* __restrict__ W,
                                                     unsigned short* __restrict__ wt) {
    int i = blockIdx.x * 256 + threadIdx.x;
    if (i < NFEAT * NHID) {
        int k = i >> 6, n = i & 63;
        wt[n * NFEAT + k] = f2bf(W[i]);
    }
}

// ---------------------------------------------------------------------------
// GEMM (MFMA bf16): support[N x 64] = x[N x 256] @ W[256 x 64], bf16 out.
// ---------------------------------------------------------------------------
__global__ __launch_bounds__(256) void gemm_kernel(const float* __restrict__ x,
                                                   const unsigned short* __restrict__ wt,
                                                   unsigned short* __restrict__ support) {
    __shared__ unsigned short Abf[64][264];  // row stride 528B, 16B-aligned
    __shared__ unsigned short Bt[64][264];   // Bt[n][k]
    const int t = threadIdx.x;
    const int row0 = blockIdx.x * 64;

    {
        const int r = t >> 6;
        const int c4 = t & 63;
        #pragma unroll
        for (int rr = 0; rr < 16; rr++) {
            int lr_ = rr * 4 + r;
            int gr = row0 + lr_;
            float4 v = make_float4(0.f, 0.f, 0.f, 0.f);
            if (gr < N_NODES) v = *(const float4*)&x[(size_t)gr * NFEAT + c4 * 4];
            ushort4 u;
            u.x = f2bf(v.x); u.y = f2bf(v.y); u.z = f2bf(v.z); u.w = f2bf(v.w);
            *(ushort4*)&Abf[lr_][c4 * 4] = u;
        }
    }
    {
        const int rB = t >> 5;
        const int ch = t & 31;
        #pragma unroll
        for (int rr = 0; rr < 8; rr++) {
            int n = rr * 8 + rB;
            uint4 v = *(const uint4*)&wt[n * NFEAT + ch * 8];
            *(uint4*)&Bt[n][ch * 8] = v;
        }
    }
    __syncthreads();

    const int lane = t & 63;
    const int w = t >> 6;
    const int m = lane & 15;
    const int q = lane >> 4;
    f32x4 acc0 = {0.f, 0.f, 0.f, 0.f};
    f32x4 acc1 = acc0, acc2 = acc0, acc3 = acc0;

    #pragma unroll
    for (int ks = 0; ks < NFEAT; ks += 32) {
        bf16x8 af = *(const bf16x8*)&Abf[w * 16 + m][ks + q * 8];
        bf16x8 b0 = *(const bf16x8*)&Bt[ 0 + m][ks + q * 8];
        bf16x8 b1 = *(const bf16x8*)&Bt[16 + m][ks + q * 8];
        bf16x8 b2 = *(const bf16x8*)&Bt[32 + m][ks + q * 8];
        bf16x8 b3 = *(const bf16x8*)&Bt[48 + m][ks + q * 8];
        acc0 = __builtin_amdgcn_mfma_f32_16x16x32_bf16(af, b0, acc0, 0, 0, 0);
        acc1 = __builtin_amdgcn_mfma_f32_16x16x32_bf16(af, b1, acc1, 0, 0, 0);
        acc2 = __builtin_amdgcn_mfma_f32_16x16x32_bf16(af, b2, acc2, 0, 0, 0);
        acc3 = __builtin_amdgcn_mfma_f32_16x16x32_bf16(af, b3, acc3, 0, 0, 0);
    }

    // C/D layout: row = q*4 + reg, col = nt*16 + m
    #pragma unroll
    for (int reg = 0; reg < 4; reg++) {
        int grow = row0 + w * 16 + q * 4 + reg;
        if (grow < N_NODES) {
            support[(size_t)grow * NHID +  0 + m] = f2bf(acc0[reg]);
            support[(size_t)grow * NHID + 16 + m] = f2bf(acc1[reg]);
            support[(size_t)grow * NHID + 32 + m] = f2bf(acc2[reg]);
            support[(size_t)grow * NHID + 48 + m] = f2bf(acc3[reg]);
        }
    }
}

// ---------------------------------------------------------------------------
// Bucket-level histogram (LDS-aggregated).
// ---------------------------------------------------------------------------
__global__ __launch_bounds__(256) void bhist_kernel(const int* __restrict__ row,
                                                    int* __restrict__ hb) {
    __shared__ int lcnt[NBUCK];
    const int t = threadIdx.x;
    for (int b = t; b < NBUCK; b += 256) lcnt[b] = 0;
    __syncthreads();
    const int e0 = blockIdx.x * CHUNK;
    #pragma unroll
    for (int i = 0; i < 16; i++) {
        int e = e0 + i * 256 + t;
        if (e < N_EDGES) atomicAdd(&lcnt[row[e] >> BSHIFT], 1);
    }
    __syncthreads();
    for (int b = t; b < NBUCK; b += 256) {
        int c = lcnt[b];
        if (c) atomicAdd(&hb[b], c);
    }
}

// ---------------------------------------------------------------------------
// Exclusive scan of bucket counts -> bucket bases; seed bucket cursors.
// ---------------------------------------------------------------------------
__global__ __launch_bounds__(1024) void bscan_kernel(const int* __restrict__ hb,
                                                     int* __restrict__ bbase,
                                                     int* __restrict__ bcur,
                                                     int* __restrict__ rowptr) {
    __shared__ int s[1024];
    const int t = threadIdx.x;
    int v = (t < NBUCK) ? hb[t] : 0;
    s[t] = v;
    __syncthreads();
    #pragma unroll
    for (int off = 1; off < 1024; off <<= 1) {
        int u = (t >= off) ? s[t - off] : 0;
        __syncthreads();
        s[t] += u;
        __syncthreads();
    }
    if (t < NBUCK) {
        int base = s[t] - v;
        bbase[t] = base;
        bcur[t] = base;
    }
    if (t == 0) rowptr[N_NODES] = N_EDGES;
}

// ---------------------------------------------------------------------------
// Pass A: scatter edges into 782 row-buckets (row >> 7).
// ---------------------------------------------------------------------------
__global__ __launch_bounds__(256) void bucket_kernel(const int* __restrict__ row,
                                                     const int* __restrict__ col,
                                                     const float* __restrict__ ew,
                                                     int* __restrict__ bcur,
                                                     int2* __restrict__ bucketed) {
    __shared__ int lcnt[NBUCK];
    __shared__ int lbase[NBUCK];
    const int t = threadIdx.x;
    for (int b = t; b < NBUCK; b += 256) lcnt[b] = 0;
    __syncthreads();

    const int e0 = blockIdx.x * CHUNK;
    int bk[16];
    int val[16];
    float w[16];
    #pragma unroll
    for (int i = 0; i < 16; i++) {
        int e = e0 + i * 256 + t;
        if (e < N_EDGES) {
            int r = row[e];
            int c = col[e];
            w[i] = ew[e];
            bk[i] = r >> BSHIFT;
            val[i] = ((r & ((1 << BSHIFT) - 1)) << 17) | c;
            atomicAdd(&lcnt[bk[i]], 1);
        } else {
            bk[i] = -1;
        }
    }
    __syncthreads();

    for (int b = t; b < NBUCK; b += 256) {
        int c = lcnt[b];
        lbase[b] = c ? atomicAdd(&bcur[b], c) : 0;
        lcnt[b] = 0;   // reuse as rank counter
    }
    __syncthreads();

    #pragma unroll
    for (int i = 0; i < 16; i++) {
        if (bk[i] >= 0) {
            int pos = lbase[bk[i]] + atomicAdd(&lcnt[bk[i]], 1);
            bucketed[pos] = make_int2(val[i], __float_as_int(w[i]));
        }
    }
}

// ---------------------------------------------------------------------------
// Pass B: per-bucket LDS counting sort; also emits rowptr. No global atomics.
// ---------------------------------------------------------------------------
__global__ __launch_bounds__(256) void place_kernel(const int* __restrict__ bbase,
                                                    const int* __restrict__ hb,
                                                    const int2* __restrict__ bucketed,
                                                    int2* __restrict__ sorted,
                                                    int* __restrict__ rowptr) {
    __shared__ int2 stage[CAP];    // 20KB
    __shared__ int2 stage2[CAP];   // 20KB
    __shared__ int hcnt[128];
    __shared__ int hs[128];
    const int t = threadIdx.x;
    const int b = blockIdx.x;
    const int bs = bbase[b];
    const int nrec = hb[b];
    const bool fit = (nrec <= CAP);

    if (t < 128) hcnt[t] = 0;
    __syncthreads();

    for (int i = t; i < nrec; i += 256) {
        int2 rec = bucketed[bs + i];
        if (fit) stage[i] = rec;
        atomicAdd(&hcnt[rec.x >> 17], 1);
    }
    __syncthreads();

    // Hillis-Steele inclusive scan over 128 counters.
    int v0 = (t < 128) ? hcnt[t] : 0;
    if (t < 128) hs[t] = v0;
    __syncthreads();
    #pragma unroll
    for (int off = 1; off < 128; off <<= 1) {
        int u = (t < 128 && t >= off) ? hs[t - off] : 0;
        __syncthreads();
        if (t < 128) hs[t] += u;
        __syncthreads();
    }
    if (t < 128) {
        int excl = hs[t] - v0;
        int r = (b << BSHIFT) + t;
        if (r < N_NODES) rowptr[r] = bs + excl;
        hcnt[t] = excl;
    }
    __syncthreads();

    if (fit) {
        for (int i = t; i < nrec; i += 256) {
            int2 rec = stage[i];
            int lr = rec.x >> 17;
            int pos = atomicAdd(&hcnt[lr], 1);
            stage2[pos] = make_int2(rec.x & 0x1FFFF, rec.y);
        }
        __syncthreads();
        for (int i = t; i < nrec; i += 256) {
            sorted[bs + i] = stage2[i];
        }
    } else {
        for (int i = t; i < nrec; i += 256) {
            int2 rec = bucketed[bs + i];
            int lr = rec.x >> 17;
            int pos = atomicAdd(&hcnt[lr], 1);
            sorted[bs + pos] = make_int2(rec.x & 0x1FFFF, rec.y);
        }
    }
}

// ---------------------------------------------------------------------------
// Gather-reduce (R13): block = 52 contiguous nodes. The block's whole sorted
// span is staged into LDS first (coalesced burst). Per-edge metadata then
// comes from uniform-address ds_read_b64 (broadcast, lgkmcnt) so the support
// gathers (vmcnt) pipeline across node boundaries with no drain points.
// Overflow beyond ECAP falls back to direct global metadata (correct, ~never).
// BN stats fused: block LDS reduce -> 128 atomics per block.
// ---------------------------------------------------------------------------
__global__ __launch_bounds__(256) void gather_kernel(const int* __restrict__ rowptr,
                                                     const int2* __restrict__ sorted,
                                                     const unsigned short* __restrict__ support,
                                                     float* __restrict__ agg,
                                                     float* __restrict__ sums) {
    __shared__ int2 ebuf[ECAP];        // 12 KB
    __shared__ int rp[NPB + 1];
    __shared__ float red[2][4][64];
    const int t = threadIdx.x;
    const int f = t & 63;
    const int wv = t >> 6;
    const int n0 = blockIdx.x * NPB;
    const int n1 = (n0 + NPB < N_NODES) ? n0 + NPB : N_NODES;
    const int nn = n1 - n0;
    float s = 0.f, s2 = 0.f;

    // Stage rowptr span.
    for (int i = t; i <= nn; i += 256) rp[i] = rowptr[n0 + i];
    __syncthreads();
    const int jb0 = rp[0];
    const int tot = rp[nn] - jb0;
    const int stot = (tot < ECAP) ? tot : ECAP;

    // Stage the block's sorted span into LDS (coalesced).
    for (int i = t; i < stot; i += 256) ebuf[i] = sorted[jb0 + i];
    __syncthreads();

    // Each wave: 13 contiguous nodes.
    const int a0n = wv * 13;
    const int b0n = (a0n + 13 < nn) ? a0n + 13 : nn;
    for (int i = a0n; i < b0n; i++) {
        const int jb = rp[i] - jb0;
        const int je = rp[i + 1] - jb0;
        const int elim = (je < stot) ? je : stot;
        float acc0 = 0.f, acc1 = 0.f;
        int e = jb;
        for (; e + 8 <= elim; e += 8) {
            int2 m0 = ebuf[e + 0];
            int2 m1 = ebuf[e + 1];
            int2 m2 = ebuf[e + 2];
            int2 m3 = ebuf[e + 3];
            int2 m4 = ebuf[e + 4];
            int2 m5 = ebuf[e + 5];
            int2 m6 = ebuf[e + 6];
            int2 m7 = ebuf[e + 7];
            float v0 = bf2f(support[m0.x * NHID + f]);
            float v1 = bf2f(support[m1.x * NHID + f]);
            float v2 = bf2f(support[m2.x * NHID + f]);
            float v3 = bf2f(support[m3.x * NHID + f]);
            float v4 = bf2f(support[m4.x * NHID + f]);
            float v5 = bf2f(support[m5.x * NHID + f]);
            float v6 = bf2f(support[m6.x * NHID + f]);
            float v7 = bf2f(support[m7.x * NHID + f]);
            acc0 = fmaf(__uint_as_float(m0.y), v0, acc0);
            acc1 = fmaf(__uint_as_float(m1.y), v1, acc1);
            acc0 = fmaf(__uint_as_float(m2.y), v2, acc0);
            acc1 = fmaf(__uint_as_float(m3.y), v3, acc1);
            acc0 = fmaf(__uint_as_float(m4.y), v4, acc0);
            acc1 = fmaf(__uint_as_float(m5.y), v5, acc1);
            acc0 = fmaf(__uint_as_float(m6.y), v6, acc0);
            acc1 = fmaf(__uint_as_float(m7.y), v7, acc1);
        }
        for (; e < elim; ++e) {
            int2 m = ebuf[e];
            acc0 = fmaf(__uint_as_float(m.y), bf2f(support[m.x * NHID + f]), acc0);
        }
        // Overflow fallback (tot > ECAP): metadata direct from global.
        for (; e < je; ++e) {
            int2 m = sorted[jb0 + e];
            acc0 = fmaf(__uint_as_float(m.y), bf2f(support[m.x * NHID + f]), acc0);
        }
        float acc = acc0 + acc1;
        agg[(size_t)(n0 + i) * NHID + f] = acc;
        s += acc;
        s2 = fmaf(acc, acc, s2);
    }

    red[0][wv][f] = s;
    red[1][wv][f] = s2;
    __syncthreads();
    if (t < 64) {
        atomicAdd(&sums[f], red[0][0][f] + red[0][1][f] + red[0][2][f] + red[0][3][f]);
    } else if (t < 128) {
        atomicAdd(&sums[64 + f], red[1][0][f] + red[1][1][f] + red[1][2][f] + red[1][3][f]);
    }
}

// ---------------------------------------------------------------------------
// Finalize: scale = gamma*rsqrt(var+eps); shift = beta - mean*scale.
// ---------------------------------------------------------------------------
__global__ __launch_bounds__(64) void finalize_kernel(const float* __restrict__ sums,
                                                      const float* __restrict__ gamma,
                                                      const float* __restrict__ beta,
                                                      float* __restrict__ scaleshift) {
    const int f = threadIdx.x;
    const float inv_n = 1.0f / (float)N_NODES;
    float mean = sums[f] * inv_n;
    float var = sums[64 + f] * inv_n - mean * mean;
    float sc = gamma[f] * rsqrtf(var + 1e-5f);
    scaleshift[f] = sc;
    scaleshift[64 + f] = beta[f] - mean * sc;
}

// ---------------------------------------------------------------------------
// Threefry-2x32, 20 rounds, key=(0,42). Hand-verified vs JAX test vector.
// ---------------------------------------------------------------------------
__device__ __forceinline__ uint32_t rotl32(uint32_t x, int d) {
    return (x << d) | (x >> (32 - d));
}

__device__ __forceinline__ void threefry2x32_0_42(uint32_t x0, uint32_t x1,
                                                  uint32_t& o0, uint32_t& o1) {
    const uint32_t k0 = 0u, k1 = 42u;
    const uint32_t k2 = k0 ^ k1 ^ 0x1BD11BDAu;
    x0 += k0; x1 += k1;
    x0 += x1; x1 = rotl32(x1, 13) ^ x0;
    x0 += x1; x1 = rotl32(x1, 15) ^ x0;
    x0 += x1; x1 = rotl32(x1, 26) ^ x0;
    x0 += x1; x1 = rotl32(x1, 6)  ^ x0;
    x0 += k1; x1 += k2 + 1u;
    x0 += x1; x1 = rotl32(x1, 17) ^ x0;
    x0 += x1; x1 = rotl32(x1, 29) ^ x0;
    x0 += x1; x1 = rotl32(x1, 16) ^ x0;
    x0 += x1; x1 = rotl32(x1, 24) ^ x0;
    x0 += k2; x1 += k0 + 2u;
    x0 += x1; x1 = rotl32(x1, 13) ^ x0;
    x0 += x1; x1 = rotl32(x1, 15) ^ x0;
    x0 += x1; x1 = rotl32(x1, 26) ^ x0;
    x0 += x1; x1 = rotl32(x1, 6)  ^ x0;
    x0 += k0; x1 += k1 + 3u;
    x0 += x1; x1 = rotl32(x1, 17) ^ x0;
    x0 += x1; x1 = rotl32(x1, 29) ^ x0;
    x0 += x1; x1 = rotl32(x1, 16) ^ x0;
    x0 += x1; x1 = rotl32(x1, 24) ^ x0;
    x0 += k1; x1 += k2 + 4u;
    x0 += x1; x1 = rotl32(x1, 13) ^ x0;
    x0 += x1; x1 = rotl32(x1, 15) ^ x0;
    x0 += x1; x1 = rotl32(x1, 26) ^ x0;
    x0 += x1; x1 = rotl32(x1, 6)  ^ x0;
    x0 += k2; x1 += k0 + 5u;
    o0 = x0; o1 = x1;
}

// ---------------------------------------------------------------------------
// Apply: BN affine + ReLU + dropout; f32 out (overwrites dead support).
// ---------------------------------------------------------------------------
__global__ __launch_bounds__(256) void apply_kernel(const float* __restrict__ agg,
                                                    const float* __restrict__ scaleshift,
                                                    float* __restrict__ out) {
    const int i = blockIdx.x * 256 + threadIdx.x;
    if (i >= N_ELEMS) return;
    const int f = i & 63;
    const float sc = scaleshift[f];
    const float sh = scaleshift[64 + f];

    uint32_t o0, o1;
    threefry2x32_0_42(0u, (uint32_t)i, o0, o1);
    uint32_t bits = o0 ^ o1;
    float u = __uint_as_float((bits >> 9) | 0x3F800000u) - 1.0f;

    float v = fmaxf(fmaf(agg[i], sc, sh), 0.0f);
    out[i] = (u < 0.7f) ? v * (1.0f / 0.7f) : 0.0f;
}

// ---------------------------------------------------------------------------
extern "C" void kernel_launch(void* const* d_in, const int* in_sizes, int n_in,
                              void* d_out, int out_size, void* d_ws, size_t ws_size,
                              hipStream_t stream) {
    const float* x     = (const float*)d_in[0];
    const int*   row   = (const int*)d_in[1];
    const int*   col   = (const int*)d_in[2];
    const float* ew    = (const float*)d_in[3];
    const float* W     = (const float*)d_in[4];
    const float* gamma = (const float*)d_in[6];
    const float* beta  = (const float*)d_in[7];
    float* out = (float*)d_out;

    float* sums       = (float*)d_ws;                      // 128 f32
    int*   hb         = (int*)(sums + 128);                // 1024 i32 (782 used)
    float* scaleshift = (float*)(hb + 1024);               // 128 f32
    int*   bbase      = (int*)(scaleshift + 128);          // 1024 i32
    int*   bcur       = bbase + 1024;                      // 1024 i32
    int*   rowptr     = bcur + 1024;                       // 100004 i32
    unsigned short* wt = (unsigned short*)(rowptr + 100004); // 16384 ushort
    float* agg        = (float*)(wt + 16384);              // 6.4M f32
    int2*  sorted     = (int2*)(agg + (size_t)N_ELEMS);    // 1.6M int2
    unsigned short* support = (unsigned short*)out;        // 6.4M bf16, in d_out
    int2*  bucketed   = (int2*)agg;                        // aliases agg (dead)

    // zero sums + hb (adjacent)
    hipMemsetAsync(d_ws, 0, (size_t)(128 + 1024) * 4, stream);

    wtprep_kernel<<<64, 256, 0, stream>>>(W, wt);
    gemm_kernel<<<(N_NODES + 63) / 64, 256, 0, stream>>>(x, wt, support);

    bhist_kernel<<<NBBLK, 256, 0, stream>>>(row, hb);
    bscan_kernel<<<1, 1024, 0, stream>>>(hb, bbase, bcur, rowptr);
    bucket_kernel<<<NBBLK, 256, 0, stream>>>(row, col, ew, bcur, bucketed);
    place_kernel<<<NBUCK, 256, 0, stream>>>(bbase, hb, bucketed, sorted, rowptr);

    gather_kernel<<<GBLK, 256, 0, stream>>>(rowptr, sorted, support, agg, sums);

    finalize_kernel<<<1, 64, 0, stream>>>(sums, gamma, beta, scaleshift);
    apply_kernel<<<(N_ELEMS + 255) / 256, 256, 0, stream>>>(agg, scaleshift, out);
}